// Round 8
// baseline (550.668 us; speedup 1.0000x reference)
//
#include <hip/hip_runtime.h>
#include <math.h>

#define Bb 8
#define Tt 256
#define MEL 128
#define Dd 192
#define NCc 20
#define ND 4                  // delta ranks (updates at t%64==0)
#define NT 32                 // theta ranks (updates at t%8==0)
#define ETAc 0.9f
#define LRc 0.1f
#define MDEC 0.99f            // 1 - ALPHA
#define EPSc 1e-5f
#define PT 4                  // pipeline rows per block
#define RTT 8                 // retrieve rows per block
#define PADD 196              // padded LDS row for float4 access
#define UPAD 193              // odd pad -> conflict-free lane-varying rows

__device__ __forceinline__ float sigmoidf_(float x) {
    return 1.0f / (1.0f + __expf(-x));
}

// coefficient of (k_i err_i^T) in M_n, valid for i<=n
__device__ __forceinline__ float memcoef(int n, int i) {
    float m = LRc, pw = LRc;
    for (int nn = i + 1; nn <= n; nn++) { pw *= ETAc; m = MDEC * m + pw; }
    return m;
}

__device__ __forceinline__ float dot4(float4 a, float4 b) {
    return a.x * b.x + a.y * b.y + a.z * b.z + a.w * b.w;
}

// ---------------------------------------------------------------------------
// setup: grid 322 x 192.
//  [0,192)   Wavo row m = Wv_a[m,:] @ Wo_a (k-outer)
//  [192]     b_avo
//  [193,241) WqtT transpose (4 rows each)
//  [241,289) WqdT transpose (4 rows each)
//  [289]     zero pooled
//  [290,322) delta k/v for (b,i): xp -> k,v
//  VERY LAST finisher (ctr==321): all-8-batch delta Gram/recurrence/u tail.
// ---------------------------------------------------------------------------
__global__ __launch_bounds__(192) void setup(
    const float* __restrict__ Wv_a, const float* __restrict__ Wo_a,
    const float* __restrict__ bv_a, const float* __restrict__ bo_a,
    const float* __restrict__ Wq_t, const float* __restrict__ Wq_d,
    const float* __restrict__ x, const float* __restrict__ W_in,
    const float* __restrict__ b_in, const float* __restrict__ Wk_d,
    const float* __restrict__ Wv_d,
    float* __restrict__ Wavo_ws, float* __restrict__ b_avo,
    float* __restrict__ WqtT, float* __restrict__ WqdT,
    float* __restrict__ Kd_ws, float* __restrict__ Vd_ws,
    float* __restrict__ Ud_ws,
    float* __restrict__ pooled, unsigned int* __restrict__ ctrs)
{
    __shared__ __align__(16) float scol[Dd];
    __shared__ __align__(16) float XR[MEL];
    __shared__ __align__(16) float XPs[Dd];
    __shared__ __align__(16) float TK[ND][Dd], TV[ND][Dd];
    __shared__ float TG[16], TMC[16];
    __shared__ bool lastFlag;

    int blk = blockIdx.x, tid = threadIdx.x;

    if (blk < 192) {                              // Wavo row m (k-outer coalesced)
        int m = blk;
        scol[tid] = Wv_a[m * Dd + tid];
        __syncthreads();
        int o = tid;
        float acc = 0.f;
        #pragma unroll 8
        for (int k = 0; k < Dd; k += 4) {
            acc += Wo_a[(k + 0) * Dd + o] * scol[k + 0];
            acc += Wo_a[(k + 1) * Dd + o] * scol[k + 1];
            acc += Wo_a[(k + 2) * Dd + o] * scol[k + 2];
            acc += Wo_a[(k + 3) * Dd + o] * scol[k + 3];
        }
        Wavo_ws[m * Dd + o] = acc;
    } else if (blk == 192) {                      // b_avo
        int o = tid;
        float s = bo_a[o];
        #pragma unroll 4
        for (int m = 0; m < Dd; m++) s += bv_a[m] * Wo_a[m * Dd + o];
        b_avo[o] = s;
    } else if (blk < 241) {                       // WqtT[e][o] = Wq_t[o][e]
        int r0 = 4 * (blk - 193);
        float4 v;
        v.x = Wq_t[(r0 + 0) * Dd + tid];
        v.y = Wq_t[(r0 + 1) * Dd + tid];
        v.z = Wq_t[(r0 + 2) * Dd + tid];
        v.w = Wq_t[(r0 + 3) * Dd + tid];
        *(float4*)&WqtT[tid * Dd + r0] = v;
    } else if (blk < 289) {                       // WqdT[e][o] = Wq_d[o][e]
        int r0 = 4 * (blk - 241);
        float4 v;
        v.x = Wq_d[(r0 + 0) * Dd + tid];
        v.y = Wq_d[(r0 + 1) * Dd + tid];
        v.z = Wq_d[(r0 + 2) * Dd + tid];
        v.w = Wq_d[(r0 + 3) * Dd + tid];
        *(float4*)&WqdT[tid * Dd + r0] = v;
    } else if (blk == 289) {                      // zero pooled
        for (int q = tid; q < Bb * Dd; q += 192) pooled[q] = 0.f;
    } else {                                      // delta k/v for (b,i)
        int q = blk - 290;
        int b = q >> 2, i = q & 3;
        if (tid < 128) XR[tid] = x[((size_t)b * Tt + 64 * i) * MEL + tid];
        __syncthreads();
        {
            int o = tid;
            float acc = b_in[o];
            #pragma unroll 8
            for (int k = 0; k < MEL; k += 4) {
                acc += W_in[(k + 0) * Dd + o] * XR[k + 0];
                acc += W_in[(k + 1) * Dd + o] * XR[k + 1];
                acc += W_in[(k + 2) * Dd + o] * XR[k + 2];
                acc += W_in[(k + 3) * Dd + o] * XR[k + 3];
            }
            XPs[o] = acc;
        }
        __syncthreads();
        {
            int o = tid;
            float ak = 0.f, av = 0.f;
            #pragma unroll 4
            for (int k = 0; k < Dd; k += 4) {
                float x0 = XPs[k + 0], x1 = XPs[k + 1], x2 = XPs[k + 2], x3 = XPs[k + 3];
                ak += Wk_d[(k + 0) * Dd + o] * x0 + Wk_d[(k + 1) * Dd + o] * x1
                    + Wk_d[(k + 2) * Dd + o] * x2 + Wk_d[(k + 3) * Dd + o] * x3;
                av += Wv_d[(k + 0) * Dd + o] * x0 + Wv_d[(k + 1) * Dd + o] * x1
                    + Wv_d[(k + 2) * Dd + o] * x2 + Wv_d[(k + 3) * Dd + o] * x3;
            }
            Kd_ws[(b * ND + i) * Dd + o] = ak;
            Vd_ws[(b * ND + i) * Dd + o] = av;
        }
    }

    // ---- common: release + last-block delta solve tail ----
    __threadfence();
    __syncthreads();
    if (tid == 0) lastFlag = (atomicAdd(&ctrs[0], 1u) == 321u);
    __syncthreads();
    if (!lastFlag) return;
    __threadfence();   // acquire

    for (int b = 0; b < Bb; b++) {
        for (int q = tid; q < ND * Dd; q += 192) {
            int i = q / Dd, c = q - i * Dd;
            TK[i][c] = ((volatile const float*)Kd_ws)[(size_t)b * ND * Dd + q];
            TV[i][c] = ((volatile const float*)Vd_ws)[(size_t)b * ND * Dd + q];
        }
        __syncthreads();
        if (tid < 16) {
            int i = tid >> 2, j = tid & 3;
            float s = 0.f;
            for (int d = 0; d < Dd; d++) s += TK[i][d] * TK[j][d];
            TG[tid] = s;
            TMC[tid] = (j <= i) ? memcoef(i, j) : 0.f;   // mc[n=i][i=j]
        }
        __syncthreads();
        {
            // column-private recurrence
            for (int i = 1; i < ND; i++) {
                float acc = TV[i][tid];
                for (int m = 0; m < i; m++)
                    acc -= TMC[(i - 1) * ND + m] * TG[i * ND + m] * TV[m][tid];
                TV[i][tid] = acc;
            }
            for (int i = 0; i < ND; i++) Vd_ws[(b * ND + i) * Dd + tid] = TV[i][tid];
            // u_i = Wq_d @ k_i via WqdT (coalesced, L2-hot)
            float u0 = 0.f, u1 = 0.f, u2 = 0.f, u3 = 0.f;
            #pragma unroll 4
            for (int e = 0; e < Dd; e++) {
                float w = ((volatile const float*)WqdT)[e * Dd + tid];
                u0 += w * TK[0][e]; u1 += w * TK[1][e];
                u2 += w * TK[2][e]; u3 += w * TK[3][e];
            }
            Ud_ws[(b * ND + 0) * Dd + tid] = u0;
            Ud_ws[(b * ND + 1) * Dd + tid] = u1;
            Ud_ws[(b * ND + 2) * Dd + tid] = u2;
            Ud_ws[(b * ND + 3) * Dd + tid] = u3;
        }
        __syncthreads();
    }
}

// ---------------------------------------------------------------------------
// pipeline: grid B*64 (4 rows/block), 192 threads. R4-verified body; even
// tiles emit theta k/v; per-batch LAST finisher runs theta solve + u~ for its
// batch (T-matrix formulation, R6-verified) in union'd LDS.
// ---------------------------------------------------------------------------
union PipeLDS {
    struct {
        float XR[PT][MEL];
        float XP[PT][Dd];
        float ED[ND][PADD], UD[ND][PADD];
        float X1[PT][Dd], X2[PT][Dd];
        float LNX[PT][Dd], HG[PT][Dd];
        float X3row[Dd];
        float WQs[PT * ND];
        float mv[PT][2];
    } p;
    struct {
        float K[NT][PADD], V[NT][PADD];
        float G[NT * NT], mcc[NT * NT];
        float T[NT * 33];
    } s;
};

__global__ __launch_bounds__(192) void pipeline(
    const float* __restrict__ x, const float* __restrict__ W_in,
    const float* __restrict__ b_in,
    const float* __restrict__ ln1_g, const float* __restrict__ ln1_b,
    const float* __restrict__ pw1_w, const float* __restrict__ pw1_b,
    const float* __restrict__ dw_w, const float* __restrict__ dw_b,
    const float* __restrict__ bn_s, const float* __restrict__ bn_b,
    const float* __restrict__ pw2_w, const float* __restrict__ pw2_b,
    const float* __restrict__ Wavo_ws, const float* __restrict__ b_avo,
    const float* __restrict__ Ed_ws, const float* __restrict__ Ud_ws,
    const float* __restrict__ Wk_t, const float* __restrict__ Wv_t,
    const float* __restrict__ WqtT,
    float* __restrict__ x3_ws, float* __restrict__ Kt_ws,
    float* __restrict__ Vt_ws, float* __restrict__ Et_ws,
    float* __restrict__ Ut_ws, unsigned int* __restrict__ ctrs)
{
    __shared__ PipeLDS U;
    __shared__ bool doSolve;

    int blk = blockIdx.x;
    int b = blk >> 6, tile = blk & 63;
    int t0 = tile * PT, n = tile >> 4;     // delta epoch, tile-uniform
    int tid = threadIdx.x;

    if (tid < 128) {
        int r = tid >> 5, c = tid & 31;
        ((float4*)U.p.XR[r])[c] = ((const float4*)&x[((size_t)b * Tt + t0 + r) * MEL])[c];
    }
    for (int q = tid; q < ND * 48 * 2; q += 192) {
        int which = q >= ND * 48;
        int qq = which ? q - ND * 48 : q;
        int i = qq / 48, c = qq - i * 48;
        if (!which) ((float4*)U.p.ED[i])[c] = ((const float4*)&Ed_ws[(b * ND + i) * Dd])[c];
        else        ((float4*)U.p.UD[i])[c] = ((const float4*)&Ud_ws[(b * ND + i) * Dd])[c];
    }
    __syncthreads();

    int o = tid;
    // xp = x @ W_in + b_in   (K=128)
    {
        float acc[PT];
        float bb = b_in[o];
        #pragma unroll
        for (int r = 0; r < PT; r++) acc[r] = bb;
        #pragma unroll 8
        for (int k = 0; k < MEL; k += 4) {
            float w0 = W_in[(k + 0) * Dd + o], w1 = W_in[(k + 1) * Dd + o];
            float w2 = W_in[(k + 2) * Dd + o], w3 = W_in[(k + 3) * Dd + o];
            #pragma unroll
            for (int r = 0; r < PT; r++) {
                float4 xv = *(const float4*)&U.p.XR[r][k];
                acc[r] += w0 * xv.x + w1 * xv.y + w2 * xv.z + w3 * xv.w;
            }
        }
        #pragma unroll
        for (int r = 0; r < PT; r++) U.p.XP[r][tid] = acc[r];
    }
    __syncthreads();

    // delta dots: WQs[r][i] = (xp_r . u_i) * coef(n,i)
    if (tid < 128) {
        int r = tid >> 5, i = (tid >> 3) & 3, c = tid & 7;
        float s = 0.f;
        const float* xp = U.p.XP[r];
        const float* u = U.p.UD[i];
        #pragma unroll
        for (int j = 0; j < 24; j++) s += xp[c * 24 + j] * u[c * 24 + j];
        s += __shfl_down(s, 4, 8);
        s += __shfl_down(s, 2, 8);
        s += __shfl_down(s, 1, 8);
        if (c == 0) {
            float coef = (i <= n) ? memcoef(n, i) : 0.f;
            U.p.WQs[r * ND + i] = s * coef;
        }
    }
    __syncthreads();

    // x1 = xp + 0.5 * sum_i WQs * err_i
    {
        #pragma unroll
        for (int r = 0; r < PT; r++) {
            float dout = U.p.WQs[r * ND + 0] * U.p.ED[0][tid] + U.p.WQs[r * ND + 1] * U.p.ED[1][tid]
                       + U.p.WQs[r * ND + 2] * U.p.ED[2][tid] + U.p.WQs[r * ND + 3] * U.p.ED[3][tid];
            U.p.X1[r][tid] = U.p.XP[r][tid] + 0.5f * dout;
        }
    }
    __syncthreads();

    // x2 = x1 + x1 @ Wavo + b_avo   (K=192)
    {
        float acc[PT];
        float bb = b_avo[o];
        #pragma unroll
        for (int r = 0; r < PT; r++) acc[r] = bb;
        #pragma unroll 8
        for (int k = 0; k < Dd; k += 4) {
            float w0 = Wavo_ws[(k + 0) * Dd + o], w1 = Wavo_ws[(k + 1) * Dd + o];
            float w2 = Wavo_ws[(k + 2) * Dd + o], w3 = Wavo_ws[(k + 3) * Dd + o];
            #pragma unroll
            for (int r = 0; r < PT; r++) {
                float4 xv = *(const float4*)&U.p.X1[r][k];
                acc[r] += w0 * xv.x + w1 * xv.y + w2 * xv.z + w3 * xv.w;
            }
        }
        #pragma unroll
        for (int r = 0; r < PT; r++) U.p.X2[r][tid] = U.p.X1[r][tid] + acc[r];
    }
    __syncthreads();

    // LN1 stats (4 groups of 32 lanes)
    if (tid < 128) {
        int r = tid >> 5, j = tid & 31;
        float s = 0.f, sq = 0.f;
        for (int d = j; d < Dd; d += 32) { float v = U.p.X2[r][d]; s += v; sq += v * v; }
        for (int off = 16; off > 0; off >>= 1) {
            s += __shfl_down(s, off, 32); sq += __shfl_down(sq, off, 32);
        }
        if (j == 0) {
            float mean = s / Dd;
            U.p.mv[r][0] = mean;
            U.p.mv[r][1] = rsqrtf(sq / Dd - mean * mean + EPSc);
        }
    }
    __syncthreads();
    {
        float g = ln1_g[tid], bb = ln1_b[tid];
        #pragma unroll
        for (int r = 0; r < PT; r++)
            U.p.LNX[r][tid] = (U.p.X2[r][tid] - U.p.mv[r][0]) * U.p.mv[r][1] * g + bb;
    }
    __syncthreads();

    // pw1 (dual halves) + GLU + dw + bn + silu
    {
        float aa[PT], gg[PT];
        float ba = pw1_b[o], bg = pw1_b[o + Dd];
        #pragma unroll
        for (int r = 0; r < PT; r++) { aa[r] = ba; gg[r] = bg; }
        #pragma unroll 4
        for (int k = 0; k < Dd; k += 4) {
            float wa0 = pw1_w[(k + 0) * 2 * Dd + o], wg0 = pw1_w[(k + 0) * 2 * Dd + Dd + o];
            float wa1 = pw1_w[(k + 1) * 2 * Dd + o], wg1 = pw1_w[(k + 1) * 2 * Dd + Dd + o];
            float wa2 = pw1_w[(k + 2) * 2 * Dd + o], wg2 = pw1_w[(k + 2) * 2 * Dd + Dd + o];
            float wa3 = pw1_w[(k + 3) * 2 * Dd + o], wg3 = pw1_w[(k + 3) * 2 * Dd + Dd + o];
            #pragma unroll
            for (int r = 0; r < PT; r++) {
                float4 xv = *(const float4*)&U.p.LNX[r][k];
                aa[r] += wa0 * xv.x + wa1 * xv.y + wa2 * xv.z + wa3 * xv.w;
                gg[r] += wg0 * xv.x + wg1 * xv.y + wg2 * xv.z + wg3 * xv.w;
            }
        }
        float dww = dw_w[o], dwb = dw_b[o], bns = bn_s[o], bnb = bn_b[o];
        #pragma unroll
        for (int r = 0; r < PT; r++) {
            float h = aa[r] * sigmoidf_(gg[r]);
            h = h * dww + dwb;
            h = h * bns + bnb;
            h = h * sigmoidf_(h);
            U.p.HG[r][tid] = h;
        }
    }
    __syncthreads();

    // pw2 + residual -> x3
    {
        float acc[PT];
        float bb = pw2_b[o];
        #pragma unroll
        for (int r = 0; r < PT; r++) acc[r] = bb;
        #pragma unroll 8
        for (int k = 0; k < Dd; k += 4) {
            float w0 = pw2_w[(k + 0) * Dd + o], w1 = pw2_w[(k + 1) * Dd + o];
            float w2 = pw2_w[(k + 2) * Dd + o], w3 = pw2_w[(k + 3) * Dd + o];
            #pragma unroll
            for (int r = 0; r < PT; r++) {
                float4 xv = *(const float4*)&U.p.HG[r][k];
                acc[r] += w0 * xv.x + w1 * xv.y + w2 * xv.z + w3 * xv.w;
            }
        }
        #pragma unroll
        for (int r = 0; r < PT; r++) {
            float v = U.p.X2[r][tid] + acc[r];
            if (r == 0) U.p.X3row[tid] = v;
            x3_ws[((size_t)b * Tt + t0 + r) * Dd + tid] = v;
        }
    }

    // theta k/v for update row (t0%8==0 <=> tile even; row 0)
    if ((tile & 1) == 0) {
        int i8 = tile >> 1;
        __syncthreads();
        float ak = 0.f, av = 0.f;
        #pragma unroll 4
        for (int k = 0; k < Dd; k += 4) {
            float x0 = U.p.X3row[k + 0], x1v = U.p.X3row[k + 1];
            float x2v = U.p.X3row[k + 2], x3v = U.p.X3row[k + 3];
            ak += Wk_t[(k + 0) * Dd + o] * x0 + Wk_t[(k + 1) * Dd + o] * x1v
                + Wk_t[(k + 2) * Dd + o] * x2v + Wk_t[(k + 3) * Dd + o] * x3v;
            av += Wv_t[(k + 0) * Dd + o] * x0 + Wv_t[(k + 1) * Dd + o] * x1v
                + Wv_t[(k + 2) * Dd + o] * x2v + Wv_t[(k + 3) * Dd + o] * x3v;
        }
        Kt_ws[(b * NT + i8) * Dd + o] = ak;
        Vt_ws[(b * NT + i8) * Dd + o] = av;
    }

    // ---- release + per-batch last-block theta solve tail ----
    __threadfence();
    __syncthreads();
    if (tid == 0) doSolve = (atomicAdd(&ctrs[1 + b], 1u) == 63u);
    __syncthreads();
    if (!doSolve) return;
    __threadfence();   // acquire

    // stage K, V
    for (int q = tid; q < NT * Dd; q += 192) {
        int i = q / Dd, c = q - i * Dd;
        U.s.K[i][c] = ((volatile const float*)Kt_ws)[(size_t)b * NT * Dd + q];
        U.s.V[i][c] = ((volatile const float*)Vt_ws)[(size_t)b * NT * Dd + q];
    }
    if (tid < NT) {
        int i = tid;
        float m = 0.f, pw = LRc;
        for (int nn = 0; nn < NT; nn++) {
            float v;
            if (nn < i) v = 0.f;
            else if (nn == i) { m = LRc; v = m; }
            else { pw *= ETAc; m = MDEC * m + pw; v = m; }
            U.s.mcc[nn * NT + i] = v;
        }
    }
    __syncthreads();
    for (int p = tid; p < NT * NT; p += 192) {       // Gram
        int i = p >> 5, j = p & 31;
        const float4* ki = (const float4*)U.s.K[i];
        const float4* kj = (const float4*)U.s.K[j];
        float s = 0.f;
        #pragma unroll 4
        for (int kk = 0; kk < 48; kk++) s += dot4(ki[kk], kj[kk]);
        U.s.G[p] = s;
    }
    __syncthreads();
    for (int p = tid; p < NT * NT; p += 192) {       // S in place over G
        int i = p >> 5, m = p & 31;
        U.s.G[p] = (m < i) ? U.s.mcc[(i - 1) * NT + m] * U.s.G[p] : 0.f;
    }
    __syncthreads();
    if (tid < NT) {                                   // T column solve
        int j = tid;
        U.s.T[j * 33 + j] = 1.f;
        for (int i = j + 1; i < NT; i++) {
            float s = 0.f;
            for (int m = j; m < i; m++) s += U.s.G[i * NT + m] * U.s.T[m * 33 + j];
            U.s.T[i * 33 + j] = -s;
        }
    }
    __syncthreads();
    {                                                 // err = T @ V (col-private)
        for (int i = 0; i < NT; i++) {
            float s = 0.f;
            for (int j = 0; j <= i; j++) s += U.s.T[i * 33 + j] * U.s.V[j][tid];
            Et_ws[(b * NT + i) * Dd + tid] = s;
        }
    }
    // u~_i = Wq_t @ k_i for all 32 ranks (two passes of 16, WqtT k-outer)
    for (int half = 0; half < 2; half++) {
        float acc[16];
        #pragma unroll
        for (int i = 0; i < 16; i++) acc[i] = 0.f;
        for (int e = 0; e < Dd; e += 4) {
            float w0 = WqtT[(e + 0) * Dd + tid], w1 = WqtT[(e + 1) * Dd + tid];
            float w2 = WqtT[(e + 2) * Dd + tid], w3 = WqtT[(e + 3) * Dd + tid];
            #pragma unroll
            for (int i = 0; i < 16; i++) {
                float4 kv = *(const float4*)&U.s.K[half * 16 + i][e];
                acc[i] += w0 * kv.x + w1 * kv.y + w2 * kv.z + w3 * kv.w;
            }
        }
        #pragma unroll
        for (int i = 0; i < 16; i++)
            Ut_ws[(b * NT + half * 16 + i) * Dd + tid] = acc[i];
    }
}

// ---------------------------------------------------------------------------
// retrieve: grid B*32 (8 rows/block), 256 threads + fused head (last block).
// ---------------------------------------------------------------------------
__global__ __launch_bounds__(256) void retrieve(
    const float* __restrict__ x3_ws, const float* __restrict__ Ut_ws,
    const float* __restrict__ Et_ws, const float* __restrict__ ln2_g,
    const float* __restrict__ ln2_b, float* __restrict__ pooled,
    const float* __restrict__ Wc, const float* __restrict__ bc,
    float* __restrict__ out, unsigned int* __restrict__ ctrs)
{
    int blk = blockIdx.x, b = blk >> 5, tile = blk & 31;
    int t0 = tile * RTT, n = tile;
    int tid = threadIdx.x;

    __shared__ float UT[NT][UPAD];       // odd pad: conflict-free lane-varying
    __shared__ __align__(16) float XS[RTT][PADD];
    __shared__ float WQ[RTT * NT];
    __shared__ float mv[RTT][2];
    __shared__ float PLD[Bb * Dd];
    __shared__ bool isLast;

    for (int q = tid; q < NT * Dd; q += 256) {
        int i = q / Dd, c = q - i * Dd;
        UT[i][c] = Ut_ws[(size_t)b * NT * Dd + q];
    }
    for (int q = tid; q < RTT * 48; q += 256) {
        int r = q / 48, c = q - r * 48;
        ((float4*)XS[r])[c] = ((const float4*)&x3_ws[((size_t)b * Tt + t0 + r) * Dd])[c];
    }
    __syncthreads();

    // dots: tid = r*32 + i ; w[r][i] = (x3_r . u~_i) * coef
    {
        int r = tid >> 5, i = tid & 31;
        const float* u = UT[i];
        const float* xr = XS[r];
        float s = 0.f;
        #pragma unroll 8
        for (int kk = 0; kk < Dd; kk++) s += u[kk] * xr[kk];
        float coef = (i <= n) ? memcoef(n, i) : 0.f;
        WQ[tid] = s * coef;
    }
    __syncthreads();

    // x4 = x3 + 0.5 * sum_i WQ * err_i
    if (tid < Dd) {
        float acc[RTT] = {};
        #pragma unroll 4
        for (int i = 0; i < NT; i++) {
            float e = Et_ws[(b * NT + i) * Dd + tid];
            #pragma unroll
            for (int r = 0; r < RTT; r++) acc[r] += WQ[r * NT + i] * e;
        }
        #pragma unroll
        for (int r = 0; r < RTT; r++) XS[r][tid] += 0.5f * acc[r];
    }
    __syncthreads();

    // LN2 stats
    {
        int r = tid >> 5, j = tid & 31;
        float s = 0.f, sq = 0.f;
        for (int d = j; d < Dd; d += 32) { float v = XS[r][d]; s += v; sq += v * v; }
        for (int off = 16; off > 0; off >>= 1) {
            s += __shfl_down(s, off, 32); sq += __shfl_down(sq, off, 32);
        }
        if (j == 0) {
            float mean = s / Dd;
            mv[r][0] = mean;
            mv[r][1] = rsqrtf(sq / Dd - mean * mean + EPSc);
        }
    }
    __syncthreads();

    if (tid < Dd) {
        float g = ln2_g[tid], bb = ln2_b[tid];
        float sum = 0.f;
        #pragma unroll
        for (int r = 0; r < RTT; r++)
            sum += (XS[r][tid] - mv[r][0]) * mv[r][1] * g + bb;
        atomicAdd(&pooled[b * Dd + tid], sum);
    }

    // -------- fused head: last block computes out = (pooled/T)@Wc + bc -----
    __threadfence();
    __syncthreads();
    if (tid == 0) isLast = (atomicAdd(&ctrs[9], 1u) == (unsigned)(Bb * 32 - 1));
    __syncthreads();
    if (!isLast) return;
    __threadfence();
    for (int q = tid; q < Bb * Dd; q += 256)
        PLD[q] = *(volatile const float*)&pooled[q];
    __syncthreads();
    if (tid < Bb * NCc) {
        int bo = tid / NCc, c = tid - bo * NCc;
        float s = 0.f;
        for (int d = 0; d < Dd; d++) s += PLD[bo * Dd + d] * Wc[d * NCc + c];
        out[tid] = s * (1.0f / Tt) + bc[c];
    }
}

extern "C" void kernel_launch(void* const* d_in, const int* in_sizes, int n_in,
                              void* d_out, int out_size, void* d_ws, size_t ws_size,
                              hipStream_t stream) {
    const float* x     = (const float*)d_in[0];
    const float* W_in  = (const float*)d_in[1];
    const float* b_in  = (const float*)d_in[2];
    const float* Wv_a  = (const float*)d_in[3];
    const float* bv_a  = (const float*)d_in[4];
    const float* Wo_a  = (const float*)d_in[5];
    const float* bo_a  = (const float*)d_in[6];
    const float* ln1_g = (const float*)d_in[7];
    const float* ln1_b = (const float*)d_in[8];
    const float* pw1_w = (const float*)d_in[9];
    const float* pw1_b = (const float*)d_in[10];
    const float* dw_w  = (const float*)d_in[11];
    const float* dw_b  = (const float*)d_in[12];
    const float* bn_s  = (const float*)d_in[13];
    const float* bn_b  = (const float*)d_in[14];
    const float* pw2_w = (const float*)d_in[15];
    const float* pw2_b = (const float*)d_in[16];
    const float* Wk_t  = (const float*)d_in[17];
    const float* Wv_t  = (const float*)d_in[18];
    const float* Wq_t  = (const float*)d_in[19];
    const float* Wk_d  = (const float*)d_in[20];
    const float* Wv_d  = (const float*)d_in[21];
    const float* Wq_d  = (const float*)d_in[22];
    const float* ln2_g = (const float*)d_in[23];
    const float* ln2_b = (const float*)d_in[24];
    const float* Wc    = (const float*)d_in[25];
    const float* bc    = (const float*)d_in[26];

    float* ws = (float*)d_ws;
    size_t off = 0;
    float* x3_ws   = ws + off; off += (size_t)Bb * Tt * Dd;
    float* Kd_ws   = ws + off; off += Bb * ND * Dd;
    float* Vd_ws   = ws + off; off += Bb * ND * Dd;   // -> err after setup tail
    float* Ud_ws   = ws + off; off += Bb * ND * Dd;
    float* Kt_ws   = ws + off; off += Bb * NT * Dd;
    float* Vt_ws   = ws + off; off += Bb * NT * Dd;
    float* Et_ws   = ws + off; off += Bb * NT * Dd;   // theta err
    float* Ut_ws   = ws + off; off += Bb * NT * Dd;
    float* pooled  = ws + off; off += Bb * Dd;
    float* Wavo_ws = ws + off; off += Dd * Dd;
    float* WqtT    = ws + off; off += Dd * Dd;
    float* WqdT    = ws + off; off += Dd * Dd;
    float* b_avo   = ws + off; off += Dd;
    unsigned int* ctrs = (unsigned int*)(ws + off); off += 16;

    hipMemsetAsync(ctrs, 0, 16 * sizeof(unsigned int), stream);

    setup<<<322, 192, 0, stream>>>(
        Wv_a, Wo_a, bv_a, bo_a, Wq_t, Wq_d,
        x, W_in, b_in, Wk_d, Wv_d,
        Wavo_ws, b_avo, WqtT, WqdT, Kd_ws, Vd_ws, Ud_ws, pooled, ctrs);
    pipeline<<<Bb * 64, 192, 0, stream>>>(
        x, W_in, b_in, ln1_g, ln1_b, pw1_w, pw1_b, dw_w, dw_b,
        bn_s, bn_b, pw2_w, pw2_b, Wavo_ws, b_avo, Vd_ws, Ud_ws,
        Wk_t, Wv_t, WqtT, x3_ws, Kt_ws, Vt_ws, Et_ws, Ut_ws, ctrs);
    retrieve<<<Bb * 32, 256, 0, stream>>>(
        x3_ws, Ut_ws, Et_ws, ln2_g, ln2_b, pooled, Wc, bc, (float*)d_out, ctrs);
}

// Round 10
// 497.467 us; speedup vs baseline: 1.1069x; 1.1069x over previous
//
#include <hip/hip_runtime.h>
#include <hip/hip_cooperative_groups.h>
#include <math.h>

namespace cg = cooperative_groups;

#define Bb 8
#define Tt 256
#define MEL 128
#define Dd 192
#define NCc 20
#define ND 4                  // delta ranks (updates at t%64==0)
#define NT 32                 // theta ranks (updates at t%8==0)
#define ETAc 0.9f
#define LRc 0.1f
#define MDEC 0.99f            // 1 - ALPHA
#define EPSc 1e-5f
#define PT 4                  // pipeline rows per block
#define RTT 8                 // retrieve rows per block
#define PADD 196              // padded LDS row for float4 access
#define UPAD 193              // odd pad -> conflict-free lane-varying rows
#define BLK_THR 256
#define NA 322                // phase A virtual blocks
#define NB 40
#define NC_ 512
#define NDp 256
#define NE 8
#define NF 256

__device__ __forceinline__ float sigmoidf_(float x) {
    return 1.0f / (1.0f + __expf(-x));
}

// coefficient of (k_i err_i^T) in M_n, valid for i<=n
__device__ __forceinline__ float memcoef(int n, int i) {
    float m = LRc, pw = LRc;
    for (int nn = i + 1; nn <= n; nn++) { pw *= ETAc; m = MDEC * m + pw; }
    return m;
}

__device__ __forceinline__ float dot4(float4 a, float4 b) {
    return a.x * b.x + a.y * b.y + a.z * b.z + a.w * b.w;
}

struct CoopArgs {
    const float *x, *W_in, *b_in, *Wv_a, *bv_a, *Wo_a, *bo_a;
    const float *ln1_g, *ln1_b, *pw1_w, *pw1_b, *dw_w, *dw_b, *bn_s, *bn_b;
    const float *pw2_w, *pw2_b, *Wk_t, *Wv_t, *Wq_t, *Wk_d, *Wv_d, *Wq_d;
    const float *ln2_g, *ln2_b, *Wc, *bc;
    float *x3_ws, *Kd_ws, *Vd_ws, *Ud_ws, *Kt_ws, *Vt_ws, *Et_ws, *Ut_ws;
    float *Sg_ws, *pooled, *Wavo_ws, *WqtT, *WqdT, *b_avo, *out;
};

struct LdsA { float col[Dd]; float XR[MEL]; float XP[Dd]; };
struct LdsB { float K4[ND][Dd]; float V4[ND][Dd]; float G[16], mc[16]; float KS[Dd]; };
struct LdsC {
    float XR[PT][MEL]; float XP[PT][Dd];
    float ED[ND][PADD], UD[ND][PADD];
    float X1[PT][Dd], X2[PT][Dd], LNX[PT][Dd], HG[PT][Dd];
    float WQs[PT * ND]; float mv[PT][2];
};
struct LdsD { float XS[Dd]; float KS[Dd]; };
struct LdsE1 { float K[NT][PADD]; };
struct LdsE2 { float S[NT * NT]; float T[NT * 33]; };
struct LdsF { float UT[NT][UPAD]; float XS[RTT][PADD]; float WQ[RTT * NT]; float mv[RTT][2]; };
struct LdsG { float PLD[Bb * Dd]; };

union LDSU {
    LdsA a; LdsB b; LdsC c; LdsD d; LdsE1 e1; LdsE2 e2; LdsF f; LdsG g;
};

// =================== Phase A: setup (322 vblocks) ===================
__device__ void phaseA(const CoopArgs& a, LdsA& L, int blk, int tid)
{
    if (blk < 192) {                              // Wavo row m (k-outer coalesced)
        int m = blk;
        if (tid < Dd) L.col[tid] = a.Wv_a[m * Dd + tid];
        __syncthreads();
        if (tid < Dd) {
            int o = tid;
            float acc = 0.f;
            #pragma unroll 8
            for (int k = 0; k < Dd; k += 4) {
                acc += a.Wo_a[(k + 0) * Dd + o] * L.col[k + 0];
                acc += a.Wo_a[(k + 1) * Dd + o] * L.col[k + 1];
                acc += a.Wo_a[(k + 2) * Dd + o] * L.col[k + 2];
                acc += a.Wo_a[(k + 3) * Dd + o] * L.col[k + 3];
            }
            a.Wavo_ws[m * Dd + o] = acc;
        }
    } else if (blk == 192) {                      // b_avo
        if (tid < Dd) {
            int o = tid;
            float s = a.bo_a[o];
            #pragma unroll 4
            for (int m = 0; m < Dd; m++) s += a.bv_a[m] * a.Wo_a[m * Dd + o];
            a.b_avo[o] = s;
        }
    } else if (blk < 241) {                       // WqtT[e][o] = Wq_t[o][e]
        int r0 = 4 * (blk - 193);
        if (tid < Dd) {
            float4 v;
            v.x = a.Wq_t[(r0 + 0) * Dd + tid];
            v.y = a.Wq_t[(r0 + 1) * Dd + tid];
            v.z = a.Wq_t[(r0 + 2) * Dd + tid];
            v.w = a.Wq_t[(r0 + 3) * Dd + tid];
            *(float4*)&a.WqtT[tid * Dd + r0] = v;
        }
    } else if (blk < 289) {                       // WqdT[e][o] = Wq_d[o][e]
        int r0 = 4 * (blk - 241);
        if (tid < Dd) {
            float4 v;
            v.x = a.Wq_d[(r0 + 0) * Dd + tid];
            v.y = a.Wq_d[(r0 + 1) * Dd + tid];
            v.z = a.Wq_d[(r0 + 2) * Dd + tid];
            v.w = a.Wq_d[(r0 + 3) * Dd + tid];
            *(float4*)&a.WqdT[tid * Dd + r0] = v;
        }
    } else if (blk == 289) {                      // zero pooled
        for (int q = tid; q < Bb * Dd; q += BLK_THR) a.pooled[q] = 0.f;
    } else if (blk < 322) {                       // delta k/v for (b,i)
        int q = blk - 290;
        int b = q >> 2, i = q & 3;
        if (tid < 128) L.XR[tid] = a.x[((size_t)b * Tt + 64 * i) * MEL + tid];
        __syncthreads();
        if (tid < Dd) {
            int o = tid;
            float acc = a.b_in[o];
            #pragma unroll 8
            for (int k = 0; k < MEL; k += 4) {
                acc += a.W_in[(k + 0) * Dd + o] * L.XR[k + 0];
                acc += a.W_in[(k + 1) * Dd + o] * L.XR[k + 1];
                acc += a.W_in[(k + 2) * Dd + o] * L.XR[k + 2];
                acc += a.W_in[(k + 3) * Dd + o] * L.XR[k + 3];
            }
            L.XP[o] = acc;
        }
        __syncthreads();
        if (tid < Dd) {
            int o = tid;
            float ak = 0.f, av = 0.f;
            #pragma unroll 4
            for (int k = 0; k < Dd; k += 4) {
                float x0 = L.XP[k + 0], x1 = L.XP[k + 1];
                float x2 = L.XP[k + 2], x3 = L.XP[k + 3];
                ak += a.Wk_d[(k + 0) * Dd + o] * x0 + a.Wk_d[(k + 1) * Dd + o] * x1
                    + a.Wk_d[(k + 2) * Dd + o] * x2 + a.Wk_d[(k + 3) * Dd + o] * x3;
                av += a.Wv_d[(k + 0) * Dd + o] * x0 + a.Wv_d[(k + 1) * Dd + o] * x1
                    + a.Wv_d[(k + 2) * Dd + o] * x2 + a.Wv_d[(k + 3) * Dd + o] * x3;
            }
            a.Kd_ws[(b * ND + i) * Dd + o] = ak;
            a.Vd_ws[(b * ND + i) * Dd + o] = av;
        }
    }
    __syncthreads();
}

// =================== Phase B: delta solve (40 vblocks) ===================
__device__ void phaseB(const CoopArgs& a, LdsB& L, int blk, int tid)
{
    int b = blk / 5, role = blk % 5;
    if (role == 0) {
        for (int q = tid; q < ND * Dd; q += BLK_THR) {
            int i = q / Dd, c = q - i * Dd;
            L.K4[i][c] = a.Kd_ws[(size_t)b * ND * Dd + q];
            L.V4[i][c] = a.Vd_ws[(size_t)b * ND * Dd + q];
        }
        __syncthreads();
        if (tid < 16) {
            int i = tid >> 2, j = tid & 3;
            float s = 0.f;
            for (int d = 0; d < Dd; d++) s += L.K4[i][d] * L.K4[j][d];
            L.G[tid] = s;
            L.mc[tid] = (j <= i) ? memcoef(i, j) : 0.f;   // mc[n=i][i=j]
        }
        __syncthreads();
        if (tid < Dd) {
            for (int i = 1; i < ND; i++) {   // column-private recurrence
                float acc = L.V4[i][tid];
                for (int m = 0; m < i; m++)
                    acc -= L.mc[(i - 1) * ND + m] * L.G[i * ND + m] * L.V4[m][tid];
                L.V4[i][tid] = acc;
            }
            for (int i = 0; i < ND; i++)
                a.Vd_ws[(b * ND + i) * Dd + tid] = L.V4[i][tid];
        }
    } else {
        int i = role - 1;
        if (tid < Dd) L.KS[tid] = a.Kd_ws[(b * ND + i) * Dd + tid];
        __syncthreads();
        if (tid < Dd) {
            int o = tid;
            float acc = 0.f;
            #pragma unroll 8
            for (int k = 0; k < Dd; k += 4) {
                acc += a.WqdT[(k + 0) * Dd + o] * L.KS[k + 0];
                acc += a.WqdT[(k + 1) * Dd + o] * L.KS[k + 1];
                acc += a.WqdT[(k + 2) * Dd + o] * L.KS[k + 2];
                acc += a.WqdT[(k + 3) * Dd + o] * L.KS[k + 3];
            }
            a.Ud_ws[(b * ND + i) * Dd + o] = acc;
        }
    }
    __syncthreads();
}

// =================== Phase C: pipeline (512 vblocks, R4-verified) =========
__device__ void phaseC(const CoopArgs& a, LdsC& L, int blk, int tid)
{
    int b = blk >> 6, tile = blk & 63;
    int t0 = tile * PT, n = tile >> 4;     // delta epoch, tile-uniform

    if (tid < 128) {
        int r = tid >> 5, c = tid & 31;
        ((float4*)L.XR[r])[c] =
            ((const float4*)&a.x[((size_t)b * Tt + t0 + r) * MEL])[c];
    }
    for (int q = tid; q < ND * 48 * 2; q += BLK_THR) {
        int which = q >= ND * 48;
        int qq = which ? q - ND * 48 : q;
        int i = qq / 48, c = qq - i * 48;
        if (!which) ((float4*)L.ED[i])[c] = ((const float4*)&a.Vd_ws[(b * ND + i) * Dd])[c];
        else        ((float4*)L.UD[i])[c] = ((const float4*)&a.Ud_ws[(b * ND + i) * Dd])[c];
    }
    __syncthreads();

    int o = tid;
    // xp = x @ W_in + b_in   (K=128)
    if (tid < Dd) {
        float acc[PT];
        float bb = a.b_in[o];
        #pragma unroll
        for (int r = 0; r < PT; r++) acc[r] = bb;
        #pragma unroll 8
        for (int k = 0; k < MEL; k += 4) {
            float w0 = a.W_in[(k + 0) * Dd + o], w1 = a.W_in[(k + 1) * Dd + o];
            float w2 = a.W_in[(k + 2) * Dd + o], w3 = a.W_in[(k + 3) * Dd + o];
            #pragma unroll
            for (int r = 0; r < PT; r++) {
                float4 xv = *(const float4*)&L.XR[r][k];
                acc[r] += w0 * xv.x + w1 * xv.y + w2 * xv.z + w3 * xv.w;
            }
        }
        #pragma unroll
        for (int r = 0; r < PT; r++) L.XP[r][tid] = acc[r];
    }
    __syncthreads();

    // delta dots: WQs[r][i] = (xp_r . u_i) * coef(n,i)
    if (tid < 128) {
        int r = tid >> 5, i = (tid >> 3) & 3, c = tid & 7;
        float s = 0.f;
        const float* xp = L.XP[r];
        const float* u = L.UD[i];
        #pragma unroll
        for (int j = 0; j < 24; j++) s += xp[c * 24 + j] * u[c * 24 + j];
        s += __shfl_down(s, 4, 8);
        s += __shfl_down(s, 2, 8);
        s += __shfl_down(s, 1, 8);
        if (c == 0) {
            float coef = (i <= n) ? memcoef(n, i) : 0.f;
            L.WQs[r * ND + i] = s * coef;
        }
    }
    __syncthreads();

    // x1 = xp + 0.5 * sum_i WQs * err_i
    if (tid < Dd) {
        #pragma unroll
        for (int r = 0; r < PT; r++) {
            float dout = L.WQs[r * ND + 0] * L.ED[0][tid]
                       + L.WQs[r * ND + 1] * L.ED[1][tid]
                       + L.WQs[r * ND + 2] * L.ED[2][tid]
                       + L.WQs[r * ND + 3] * L.ED[3][tid];
            L.X1[r][tid] = L.XP[r][tid] + 0.5f * dout;
        }
    }
    __syncthreads();

    // x2 = x1 + x1 @ Wavo + b_avo   (K=192)
    if (tid < Dd) {
        float acc[PT];
        float bb = a.b_avo[o];
        #pragma unroll
        for (int r = 0; r < PT; r++) acc[r] = bb;
        #pragma unroll 8
        for (int k = 0; k < Dd; k += 4) {
            float w0 = a.Wavo_ws[(k + 0) * Dd + o], w1 = a.Wavo_ws[(k + 1) * Dd + o];
            float w2 = a.Wavo_ws[(k + 2) * Dd + o], w3 = a.Wavo_ws[(k + 3) * Dd + o];
            #pragma unroll
            for (int r = 0; r < PT; r++) {
                float4 xv = *(const float4*)&L.X1[r][k];
                acc[r] += w0 * xv.x + w1 * xv.y + w2 * xv.z + w3 * xv.w;
            }
        }
        #pragma unroll
        for (int r = 0; r < PT; r++) L.X2[r][tid] = L.X1[r][tid] + acc[r];
    }
    __syncthreads();

    // LN1 stats (4 groups of 32 lanes)
    if (tid < 128) {
        int r = tid >> 5, j = tid & 31;
        float s = 0.f, sq = 0.f;
        for (int d = j; d < Dd; d += 32) { float v = L.X2[r][d]; s += v; sq += v * v; }
        for (int off = 16; off > 0; off >>= 1) {
            s += __shfl_down(s, off, 32); sq += __shfl_down(sq, off, 32);
        }
        if (j == 0) {
            float mean = s / Dd;
            L.mv[r][0] = mean;
            L.mv[r][1] = rsqrtf(sq / Dd - mean * mean + EPSc);
        }
    }
    __syncthreads();
    if (tid < Dd) {
        float g = a.ln1_g[tid], bb = a.ln1_b[tid];
        #pragma unroll
        for (int r = 0; r < PT; r++)
            L.LNX[r][tid] = (L.X2[r][tid] - L.mv[r][0]) * L.mv[r][1] * g + bb;
    }
    __syncthreads();

    // pw1 (dual halves) + GLU + dw + bn + silu
    if (tid < Dd) {
        float aa[PT], gg[PT];
        float ba = a.pw1_b[o], bg = a.pw1_b[o + Dd];
        #pragma unroll
        for (int r = 0; r < PT; r++) { aa[r] = ba; gg[r] = bg; }
        #pragma unroll 4
        for (int k = 0; k < Dd; k += 4) {
            float wa0 = a.pw1_w[(k + 0) * 2 * Dd + o], wg0 = a.pw1_w[(k + 0) * 2 * Dd + Dd + o];
            float wa1 = a.pw1_w[(k + 1) * 2 * Dd + o], wg1 = a.pw1_w[(k + 1) * 2 * Dd + Dd + o];
            float wa2 = a.pw1_w[(k + 2) * 2 * Dd + o], wg2 = a.pw1_w[(k + 2) * 2 * Dd + Dd + o];
            float wa3 = a.pw1_w[(k + 3) * 2 * Dd + o], wg3 = a.pw1_w[(k + 3) * 2 * Dd + Dd + o];
            #pragma unroll
            for (int r = 0; r < PT; r++) {
                float4 xv = *(const float4*)&L.LNX[r][k];
                aa[r] += wa0 * xv.x + wa1 * xv.y + wa2 * xv.z + wa3 * xv.w;
                gg[r] += wg0 * xv.x + wg1 * xv.y + wg2 * xv.z + wg3 * xv.w;
            }
        }
        float dww = a.dw_w[o], dwb = a.dw_b[o], bns = a.bn_s[o], bnb = a.bn_b[o];
        #pragma unroll
        for (int r = 0; r < PT; r++) {
            float h = aa[r] * sigmoidf_(gg[r]);
            h = h * dww + dwb;
            h = h * bns + bnb;
            h = h * sigmoidf_(h);
            L.HG[r][tid] = h;
        }
    }
    __syncthreads();

    // pw2 + residual -> x3
    if (tid < Dd) {
        float acc[PT];
        float bb = a.pw2_b[o];
        #pragma unroll
        for (int r = 0; r < PT; r++) acc[r] = bb;
        #pragma unroll 8
        for (int k = 0; k < Dd; k += 4) {
            float w0 = a.pw2_w[(k + 0) * Dd + o], w1 = a.pw2_w[(k + 1) * Dd + o];
            float w2 = a.pw2_w[(k + 2) * Dd + o], w3 = a.pw2_w[(k + 3) * Dd + o];
            #pragma unroll
            for (int r = 0; r < PT; r++) {
                float4 xv = *(const float4*)&L.HG[r][k];
                acc[r] += w0 * xv.x + w1 * xv.y + w2 * xv.z + w3 * xv.w;
            }
        }
        #pragma unroll
        for (int r = 0; r < PT; r++)
            a.x3_ws[((size_t)b * Tt + t0 + r) * Dd + tid] = L.X2[r][tid] + acc[r];
    }
    __syncthreads();
}

// =================== Phase D: theta k/v/u~ (256 vblocks) ===================
__device__ void phaseD(const CoopArgs& a, LdsD& L, int blk, int tid)
{
    int b = blk >> 5, i = blk & 31;
    if (tid < Dd) L.XS[tid] = a.x3_ws[((size_t)b * Tt + 8 * i) * Dd + tid];
    __syncthreads();
    if (tid < Dd) {
        int o = tid;
        float ak = 0.f, av = 0.f;
        #pragma unroll 4
        for (int k = 0; k < Dd; k += 4) {
            float x0 = L.XS[k + 0], x1 = L.XS[k + 1];
            float x2 = L.XS[k + 2], x3 = L.XS[k + 3];
            ak += a.Wk_t[(k + 0) * Dd + o] * x0 + a.Wk_t[(k + 1) * Dd + o] * x1
                + a.Wk_t[(k + 2) * Dd + o] * x2 + a.Wk_t[(k + 3) * Dd + o] * x3;
            av += a.Wv_t[(k + 0) * Dd + o] * x0 + a.Wv_t[(k + 1) * Dd + o] * x1
                + a.Wv_t[(k + 2) * Dd + o] * x2 + a.Wv_t[(k + 3) * Dd + o] * x3;
        }
        a.Kt_ws[(b * NT + i) * Dd + o] = ak;
        a.Vt_ws[(b * NT + i) * Dd + o] = av;
        L.KS[o] = ak;
    }
    __syncthreads();
    if (tid < Dd) {
        int o = tid;
        float au = 0.f;
        #pragma unroll 8
        for (int k = 0; k < Dd; k += 4) {
            au += a.WqtT[(k + 0) * Dd + o] * L.KS[k + 0]
                + a.WqtT[(k + 1) * Dd + o] * L.KS[k + 1]
                + a.WqtT[(k + 2) * Dd + o] * L.KS[k + 2]
                + a.WqtT[(k + 3) * Dd + o] * L.KS[k + 3];
        }
        a.Ut_ws[(b * NT + i) * Dd + o] = au;
    }
    __syncthreads();
}

// =================== Phase E1: Gram -> S (8 vblocks) ===================
__device__ void phaseE1(const CoopArgs& a, LdsE1& L, int blk, int tid)
{
    int b = blk;
    for (int q = tid; q < NT * 48; q += BLK_THR) {
        int i = q / 48, c = q - i * 48;
        ((float4*)L.K[i])[c] = ((const float4*)&a.Kt_ws[(b * NT + i) * Dd])[c];
    }
    __syncthreads();
    for (int p = tid; p < NT * NT; p += BLK_THR) {
        int i = p >> 5, m = p & 31;
        float sv = 0.f;
        if (m < i) {
            const float4* ki = (const float4*)L.K[i];
            const float4* km = (const float4*)L.K[m];
            float s = 0.f;
            #pragma unroll 4
            for (int kk = 0; kk < 48; kk++) s += dot4(ki[kk], km[kk]);
            sv = memcoef(i - 1, m) * s;
        }
        a.Sg_ws[(size_t)b * NT * NT + p] = sv;
    }
    __syncthreads();
}

// =================== Phase E2: T-solve + err = T@V (8 vblocks) ============
__device__ void phaseE2(const CoopArgs& a, LdsE2& L, int blk, int tid)
{
    int b = blk;
    for (int p = tid; p < NT * NT; p += BLK_THR)
        L.S[p] = a.Sg_ws[(size_t)b * NT * NT + p];
    __syncthreads();
    if (tid < NT) {                                   // T column solve (R6-verified)
        int j = tid;
        L.T[j * 33 + j] = 1.f;
        for (int i = j + 1; i < NT; i++) {
            float s = 0.f;
            for (int m = j; m < i; m++) s += L.S[i * NT + m] * L.T[m * 33 + j];
            L.T[i * 33 + j] = -s;
        }
    }
    __syncthreads();
    if (tid < Dd) {                                   // err = T @ V, V coalesced
        float accv[NT];
        #pragma unroll
        for (int i = 0; i < NT; i++) accv[i] = 0.f;
        #pragma unroll
        for (int j = 0; j < NT; j++) {
            float v = a.Vt_ws[(b * NT + j) * Dd + tid];
            #pragma unroll
            for (int i = 0; i < NT; i++)
                if (i >= j) accv[i] += L.T[i * 33 + j] * v;
        }
        for (int i = 0; i < NT; i++)
            a.Et_ws[(b * NT + i) * Dd + tid] = accv[i];
    }
    __syncthreads();
}

// =================== Phase F: retrieve (256 vblocks, R7-verified) ==========
__device__ void phaseF(const CoopArgs& a, LdsF& L, int blk, int tid)
{
    int b = blk >> 5, tile = blk & 31;
    int t0 = tile * RTT, n = tile;

    for (int q = tid; q < NT * Dd; q += BLK_THR) {
        int i = q / Dd, c = q - i * Dd;
        L.UT[i][c] = a.Ut_ws[(size_t)b * NT * Dd + q];
    }
    for (int q = tid; q < RTT * 48; q += BLK_THR) {
        int r = q / 48, c = q - r * 48;
        ((float4*)L.XS[r])[c] =
            ((const float4*)&a.x3_ws[((size_t)b * Tt + t0 + r) * Dd])[c];
    }
    __syncthreads();

    // dots: tid = r*32 + i ; w[r][i] = (x3_r . u~_i) * coef
    {
        int r = tid >> 5, i = tid & 31;
        const float* u = L.UT[i];
        const float* xr = L.XS[r];
        float s = 0.f;
        #pragma unroll 8
        for (int kk = 0; kk < Dd; kk++) s += u[kk] * xr[kk];
        float coef = (i <= n) ? memcoef(n, i) : 0.f;
        L.WQ[tid] = s * coef;
    }
    __syncthreads();

    // x4 = x3 + 0.5 * sum_i WQ * err_i
    if (tid < Dd) {
        float acc[RTT] = {};
        #pragma unroll 4
        for (int i = 0; i < NT; i++) {
            float e = a.Et_ws[(b * NT + i) * Dd + tid];
            #pragma unroll
            for (int r = 0; r < RTT; r++) acc[r] += L.WQ[r * NT + i] * e;
        }
        #pragma unroll
        for (int r = 0; r < RTT; r++) L.XS[r][tid] += 0.5f * acc[r];
    }
    __syncthreads();

    // LN2 stats
    {
        int r = tid >> 5, j = tid & 31;
        float s = 0.f, sq = 0.f;
        for (int d = j; d < Dd; d += 32) { float v = L.XS[r][d]; s += v; sq += v * v; }
        for (int off = 16; off > 0; off >>= 1) {
            s += __shfl_down(s, off, 32); sq += __shfl_down(sq, off, 32);
        }
        if (j == 0) {
            float mean = s / Dd;
            L.mv[r][0] = mean;
            L.mv[r][1] = rsqrtf(sq / Dd - mean * mean + EPSc);
        }
    }
    __syncthreads();

    if (tid < Dd) {
        float g = a.ln2_g[tid], bb = a.ln2_b[tid];
        float sum = 0.f;
        #pragma unroll
        for (int r = 0; r < RTT; r++)
            sum += (L.XS[r][tid] - L.mv[r][0]) * L.mv[r][1] * g + bb;
        atomicAdd(&a.pooled[b * Dd + tid], sum);
    }
    __syncthreads();
}

// =================== Phase G: head (1 vblock) ===================
__device__ void phaseG(const CoopArgs& a, LdsG& L, int tid)
{
    for (int q = tid; q < Bb * Dd; q += BLK_THR) L.PLD[q] = a.pooled[q];
    __syncthreads();
    if (tid < Bb * NCc) {
        int bo = tid / NCc, c = tid - bo * NCc;
        float s = 0.f;
        for (int d = 0; d < Dd; d++) s += L.PLD[bo * Dd + d] * a.Wc[d * NCc + c];
        a.out[tid] = s * (1.0f / Tt) + a.bc[c];
    }
    __syncthreads();
}

// =================== Cooperative fused kernel ===================
__global__ __launch_bounds__(BLK_THR, 2) void fused(CoopArgs a)
{
    cg::grid_group grid = cg::this_grid();
    __shared__ LDSU U;
    int tid = threadIdx.x;

    for (int vb = blockIdx.x; vb < NA; vb += gridDim.x) phaseA(a, U.a, vb, tid);
    grid.sync();
    for (int vb = blockIdx.x; vb < NB; vb += gridDim.x) phaseB(a, U.b, vb, tid);
    grid.sync();
    for (int vb = blockIdx.x; vb < NC_; vb += gridDim.x) phaseC(a, U.c, vb, tid);
    grid.sync();
    for (int vb = blockIdx.x; vb < NDp; vb += gridDim.x) phaseD(a, U.d, vb, tid);
    grid.sync();
    for (int vb = blockIdx.x; vb < NE; vb += gridDim.x) phaseE1(a, U.e1, vb, tid);
    grid.sync();
    for (int vb = blockIdx.x; vb < NE; vb += gridDim.x) phaseE2(a, U.e2, vb, tid);
    grid.sync();
    for (int vb = blockIdx.x; vb < NF; vb += gridDim.x) phaseF(a, U.f, vb, tid);
    grid.sync();
    if (blockIdx.x == 0) phaseG(a, U.g, tid);
}

// =================== Fallback standalone kernels ===================
__global__ __launch_bounds__(BLK_THR) void kA(CoopArgs a) { __shared__ LdsA L; phaseA(a, L, blockIdx.x, threadIdx.x); }
__global__ __launch_bounds__(BLK_THR) void kB(CoopArgs a) { __shared__ LdsB L; phaseB(a, L, blockIdx.x, threadIdx.x); }
__global__ __launch_bounds__(BLK_THR) void kC(CoopArgs a) { __shared__ LdsC L; phaseC(a, L, blockIdx.x, threadIdx.x); }
__global__ __launch_bounds__(BLK_THR) void kD(CoopArgs a) { __shared__ LdsD L; phaseD(a, L, blockIdx.x, threadIdx.x); }
__global__ __launch_bounds__(BLK_THR) void kE1(CoopArgs a){ __shared__ LdsE1 L; phaseE1(a, L, blockIdx.x, threadIdx.x); }
__global__ __launch_bounds__(BLK_THR) void kE2(CoopArgs a){ __shared__ LdsE2 L; phaseE2(a, L, blockIdx.x, threadIdx.x); }
__global__ __launch_bounds__(BLK_THR) void kF(CoopArgs a) { __shared__ LdsF L; phaseF(a, L, blockIdx.x, threadIdx.x); }
__global__ __launch_bounds__(BLK_THR) void kG(CoopArgs a) { __shared__ LdsG L; phaseG(a, L, threadIdx.x); }

extern "C" void kernel_launch(void* const* d_in, const int* in_sizes, int n_in,
                              void* d_out, int out_size, void* d_ws, size_t ws_size,
                              hipStream_t stream) {
    float* ws = (float*)d_ws;
    size_t off = 0;
    float* x3_ws   = ws + off; off += (size_t)Bb * Tt * Dd;
    float* Kd_ws   = ws + off; off += Bb * ND * Dd;
    float* Vd_ws   = ws + off; off += Bb * ND * Dd;   // -> delta err after phase B
    float* Ud_ws   = ws + off; off += Bb * ND * Dd;
    float* Kt_ws   = ws + off; off += Bb * NT * Dd;
    float* Vt_ws   = ws + off; off += Bb * NT * Dd;
    float* Et_ws   = ws + off; off += Bb * NT * Dd;   // theta err
    float* Ut_ws   = ws + off; off += Bb * NT * Dd;
    float* Sg_ws   = ws + off; off += Bb * NT * NT;
    float* pooled  = ws + off; off += Bb * Dd;
    float* Wavo_ws = ws + off; off += Dd * Dd;
    float* WqtT    = ws + off; off += Dd * Dd;
    float* WqdT    = ws + off; off += Dd * Dd;
    float* b_avo   = ws + off; off += Dd;

    CoopArgs a;
    a.x     = (const float*)d_in[0];
    a.W_in  = (const float*)d_in[1];
    a.b_in  = (const float*)d_in[2];
    a.Wv_a  = (const float*)d_in[3];
    a.bv_a  = (const float*)d_in[4];
    a.Wo_a  = (const float*)d_in[5];
    a.bo_a  = (const float*)d_in[6];
    a.ln1_g = (const float*)d_in[7];
    a.ln1_b = (const float*)d_in[8];
    a.pw1_w = (const float*)d_in[9];
    a.pw1_b = (const float*)d_in[10];
    a.dw_w  = (const float*)d_in[11];
    a.dw_b  = (const float*)d_in[12];
    a.bn_s  = (const float*)d_in[13];
    a.bn_b  = (const float*)d_in[14];
    a.pw2_w = (const float*)d_in[15];
    a.pw2_b = (const float*)d_in[16];
    a.Wk_t  = (const float*)d_in[17];
    a.Wv_t  = (const float*)d_in[18];
    a.Wq_t  = (const float*)d_in[19];
    a.Wk_d  = (const float*)d_in[20];
    a.Wv_d  = (const float*)d_in[21];
    a.Wq_d  = (const float*)d_in[22];
    a.ln2_g = (const float*)d_in[23];
    a.ln2_b = (const float*)d_in[24];
    a.Wc    = (const float*)d_in[25];
    a.bc    = (const float*)d_in[26];
    a.x3_ws = x3_ws;   a.Kd_ws = Kd_ws;  a.Vd_ws = Vd_ws;  a.Ud_ws = Ud_ws;
    a.Kt_ws = Kt_ws;   a.Vt_ws = Vt_ws;  a.Et_ws = Et_ws;  a.Ut_ws = Ut_ws;
    a.Sg_ws = Sg_ws;   a.pooled = pooled; a.Wavo_ws = Wavo_ws;
    a.WqtT = WqtT;     a.WqdT = WqdT;     a.b_avo = b_avo;
    a.out = (float*)d_out;

    // ---- decide coop vs fallback (host-side queries only; capture-safe) ----
    int dev = 0;
    (void)hipGetDevice(&dev);
    int numCU = 0;
    (void)hipDeviceGetAttribute(&numCU, hipDeviceAttributeMultiprocessorCount, dev);
    int nbPerCU = 0;
    hipError_t qe = hipOccupancyMaxActiveBlocksPerMultiprocessor(&nbPerCU, fused, BLK_THR, 0);

    bool coop_ok = (qe == hipSuccess) && (numCU > 0) && (nbPerCU > 0)
                   && ((long)nbPerCU * numCU >= 64);
    if (coop_ok) {
        long cap = (long)nbPerCU * numCU;
        int grid = (int)(cap < NC_ ? cap : NC_);
        void* kargs[] = { &a };
        hipError_t le = hipLaunchCooperativeKernel(
            reinterpret_cast<void*>(fused), dim3(grid), dim3(BLK_THR), kargs, 0, stream);
        if (le == hipSuccess) return;
    }

    // ---- fallback: same phases as 8 plain kernels (stream-ordered) ----
    kA<<<NA, BLK_THR, 0, stream>>>(a);
    kB<<<NB, BLK_THR, 0, stream>>>(a);
    kC<<<NC_, BLK_THR, 0, stream>>>(a);
    kD<<<NDp, BLK_THR, 0, stream>>>(a);
    kE1<<<NE, BLK_THR, 0, stream>>>(a);
    kE2<<<NE, BLK_THR, 0, stream>>>(a);
    kF<<<NF, BLK_THR, 0, stream>>>(a);
    kG<<<1, BLK_THR, 0, stream>>>(a);
}